// Round 1
// baseline (1719.315 us; speedup 1.0000x reference)
//
#include <hip/hip_runtime.h>
#include <hip/hip_cooperative_groups.h>

namespace cg = cooperative_groups;

#define BATCHES 32
#define CIN     64
#define COUT    8
#define HWPIX   65536      // 256*256
#define KSTEPS  11
#define NSTEPS  10         // K_STEPS - 1
#define BPB     8          // blocks per batch
#define GRID    (BATCHES*BPB)   // 256 blocks = 1 per CU
#define TPB     1024
#define PIXB    (HWPIX/BPB)     // 8192 pixels per block
#define GROUPS  2               // 2 float4-groups -> 8 px/thread
#define CSTR    12              // candidate stride in floats: [prob, idx, feat0..7, pad, pad]

union F4 { float4 v; float a[4]; };

__global__ __launch_bounds__(TPB, 4)
void sbseg_kernel(const float* __restrict__ x, const float* __restrict__ rnd,
                  const float* __restrict__ Wc, const float* __restrict__ bcv,
                  const float* __restrict__ gatep, const float* __restrict__ lsigp,
                  float* __restrict__ out, float* __restrict__ ws)
{
    cg::grid_group grid = cg::this_grid();

    __shared__ float sW[CIN][COUT];   // [c][o] for contiguous per-c reads
    __shared__ float sRed[2 * (TPB/64)];
    __shared__ float sSeed[COUT];
    __shared__ float sBestP;
    __shared__ int   sBestI;
    __shared__ int   sWinB;

    const int tid   = threadIdx.x;
    const int bid   = blockIdx.x;
    const int batch = bid / BPB;
    const int binb  = bid - batch * BPB;
    const int pbase = binb * PIXB;

    // stage conv weights into LDS, transposed to [c][o]
    if (tid < CIN * COUT) {
        int o = tid >> 6, c = tid & 63;      // Wc is [COUT][CIN] row-major
        sW[c][o] = Wc[tid];
    }
    __syncthreads();

    const float gate = gatep[0];
    const float sigma = expf(lsigp[0]);
    const float nrs = -1.0f / sigma;
    float cb[COUT];
#pragma unroll
    for (int o = 0; o < COUT; ++o) cb[o] = bcv[o];

    // persistent per-thread state: 8 pixels
    float feat[GROUPS][COUT][4];
    float scope[GROUPS][4];
    float rv[GROUPS][4];

#pragma unroll
    for (int g = 0; g < GROUPS; ++g)
#pragma unroll
        for (int o = 0; o < COUT; ++o)
#pragma unroll
            for (int j = 0; j < 4; ++j) feat[g][o][j] = 0.0f;

    // ---- 1x1 conv: feat[o] = sum_c W[o][c] * x[b,c,p] ----
    const float* xb = x + (size_t)batch * CIN * HWPIX + pbase + tid * 4;
#pragma unroll 2
    for (int c = 0; c < CIN; ++c) {
        F4 w0, w1;
        w0.v = *(const float4*)&sW[c][0];
        w1.v = *(const float4*)&sW[c][4];
        const float* xc = xb + (size_t)c * HWPIX;
#pragma unroll
        for (int g = 0; g < GROUPS; ++g) {
            F4 xv; xv.v = *(const float4*)(xc + g * (PIXB / GROUPS));
#pragma unroll
            for (int j = 0; j < 4; ++j) {
                feat[g][0][j] = fmaf(w0.a[0], xv.a[j], feat[g][0][j]);
                feat[g][1][j] = fmaf(w0.a[1], xv.a[j], feat[g][1][j]);
                feat[g][2][j] = fmaf(w0.a[2], xv.a[j], feat[g][2][j]);
                feat[g][3][j] = fmaf(w0.a[3], xv.a[j], feat[g][3][j]);
                feat[g][4][j] = fmaf(w1.a[0], xv.a[j], feat[g][4][j]);
                feat[g][5][j] = fmaf(w1.a[1], xv.a[j], feat[g][5][j]);
                feat[g][6][j] = fmaf(w1.a[2], xv.a[j], feat[g][6][j]);
                feat[g][7][j] = fmaf(w1.a[3], xv.a[j], feat[g][7][j]);
            }
        }
    }

    // ---- feat = gate*(conv + b) + uv ; load rand ; scope = 1 ----
    const float dstep = 2.0f / 255.0f;
    const float* rb = rnd + (size_t)batch * HWPIX + pbase + tid * 4;
#pragma unroll
    for (int g = 0; g < GROUPS; ++g) {
        F4 r4; r4.v = *(const float4*)(rb + g * (PIXB / GROUPS));
#pragma unroll
        for (int j = 0; j < 4; ++j) {
            rv[g][j] = r4.a[j];
            int p = pbase + g * (PIXB / GROUPS) + tid * 4 + j;
            float gx = -1.0f + dstep * (float)(p >> 8);   // row channel (C_OUT-2)
            float gy = -1.0f + dstep * (float)(p & 255);  // col channel (C_OUT-1)
#pragma unroll
            for (int o = 0; o < COUT; ++o) {
                float u = (o == COUT - 2) ? gx : ((o == COUT - 1) ? gy : 0.0f);
                feat[g][o][j] = gate * (feat[g][o][j] + cb[o]) + u;
            }
            scope[g][j] = 1.0f;
        }
    }

    float* masksOut  = out;
    float* scopesOut = out + (size_t)BATCHES * KSTEPS * HWPIX;

    // scopes[:,0,:,:] = 1
    {
        F4 one; one.a[0] = one.a[1] = one.a[2] = one.a[3] = 1.0f;
#pragma unroll
        for (int g = 0; g < GROUPS; ++g)
            *(float4*)(scopesOut + (size_t)batch * KSTEPS * HWPIX + pbase + tid * 4 + g * (PIXB / GROUPS)) = one.v;
    }

    // ---- stick-breaking loop ----
    for (int k = 0; k < NSTEPS; ++k) {
        // 1) local argmax of prob = rand * scope (tie -> lowest index)
        float bp = -1.0f; int bi = 0x7FFFFFFF;
#pragma unroll
        for (int g = 0; g < GROUPS; ++g)
#pragma unroll
            for (int j = 0; j < 4; ++j) {
                float pr = rv[g][j] * scope[g][j];
                int idx = pbase + g * (PIXB / GROUPS) + tid * 4 + j;
                if (pr > bp) { bp = pr; bi = idx; }   // ascending idx order => strict > keeps first
            }
        // wave reduce (64 lanes)
#pragma unroll
        for (int off = 32; off > 0; off >>= 1) {
            float op = __shfl_down(bp, off);
            int   oi = __shfl_down(bi, off);
            if (op > bp || (op == bp && oi < bi)) { bp = op; bi = oi; }
        }
        int wv = tid >> 6;
        if ((tid & 63) == 0) { sRed[wv * 2] = bp; ((int*)sRed)[wv * 2 + 1] = bi; }
        __syncthreads();
        if (tid == 0) {
            float p = sRed[0]; int i = ((int*)sRed)[1];
            for (int w = 1; w < TPB / 64; ++w) {
                float op = sRed[w * 2]; int oi = ((int*)sRed)[w * 2 + 1];
                if (op > p || (op == p && oi < i)) { p = op; i = oi; }
            }
            sBestP = p; sBestI = i;
        }
        __syncthreads();
        const float bestP = sBestP; const int bestI = sBestI;

        // 2) owner thread writes candidate {prob, idx, feat[8]} (double-buffered by parity)
        float* myCand = ws + ((size_t)((k & 1) * GRID + bid)) * CSTR;
#pragma unroll
        for (int g = 0; g < GROUPS; ++g)
#pragma unroll
            for (int j = 0; j < 4; ++j) {
                int idx = pbase + g * (PIXB / GROUPS) + tid * 4 + j;
                if (idx == bestI) {
                    myCand[0] = bestP;
                    ((int*)myCand)[1] = bestI;
#pragma unroll
                    for (int o = 0; o < COUT; ++o) myCand[2 + o] = feat[g][o][j];
                }
            }
        __threadfence();
        grid.sync();

        // 3) every block reduces its batch's BPB candidates (redundantly; L2 broadcast)
        if (tid < 64) {
            float p = -1.0f; int i = 0x7FFFFFFF; int wb = 0;
            if (tid < BPB) {
                const float* cc = ws + ((size_t)((k & 1) * GRID + batch * BPB + tid)) * CSTR;
                p = cc[0]; i = ((const int*)cc)[1]; wb = tid;
            }
#pragma unroll
            for (int off = 32; off > 0; off >>= 1) {
                float op = __shfl_down(p, off);
                int   oi = __shfl_down(i, off);
                int   ob = __shfl_down(wb, off);
                if (op > p || (op == p && oi < i)) { p = op; i = oi; wb = ob; }
            }
            if (tid == 0) sWinB = wb;
        }
        __syncthreads();
        if (tid < COUT)
            sSeed[tid] = ws[((size_t)((k & 1) * GRID + batch * BPB + sWinB)) * CSTR + 2 + tid];
        __syncthreads();

        float sd[COUT];
#pragma unroll
        for (int o = 0; o < COUT; ++o) sd[o] = sSeed[o];

        // 4) pointwise: alpha = clip(exp(-sqdist/sigma)); mask = scope*a; scope *= 1-a
#pragma unroll
        for (int g = 0; g < GROUPS; ++g) {
            F4 mo, so;
#pragma unroll
            for (int j = 0; j < 4; ++j) {
                float sq = 0.0f;
#pragma unroll
                for (int o = 0; o < COUT; ++o) {
                    float d = feat[g][o][j] - sd[o];
                    sq = fmaf(d, d, sq);
                }
                float alpha = expf(sq * nrs);
                alpha = fminf(fmaxf(alpha, 0.01f), 0.99f);
                mo.a[j] = scope[g][j] * alpha;
                scope[g][j] *= (1.0f - alpha);
                so.a[j] = scope[g][j];
            }
            size_t off = (size_t)pbase + tid * 4 + g * (PIXB / GROUPS);
            *(float4*)(masksOut  + ((size_t)(batch * KSTEPS + k))     * HWPIX + off) = mo.v;
            *(float4*)(scopesOut + ((size_t)(batch * KSTEPS + k + 1)) * HWPIX + off) = so.v;
        }
    }

    // masks[:,K-1] = remaining scope
#pragma unroll
    for (int g = 0; g < GROUPS; ++g) {
        F4 so;
#pragma unroll
        for (int j = 0; j < 4; ++j) so.a[j] = scope[g][j];
        *(float4*)(masksOut + ((size_t)(batch * KSTEPS + NSTEPS)) * HWPIX
                   + pbase + tid * 4 + g * (PIXB / GROUPS)) = so.v;
    }
}

extern "C" void kernel_launch(void* const* d_in, const int* in_sizes, int n_in,
                              void* d_out, int out_size, void* d_ws, size_t ws_size,
                              hipStream_t stream) {
    const float* x    = (const float*)d_in[0];
    const float* rnd  = (const float*)d_in[1];
    const float* Wc   = (const float*)d_in[2];
    const float* bcv  = (const float*)d_in[3];
    const float* gate = (const float*)d_in[4];
    const float* lsig = (const float*)d_in[5];
    float* out = (float*)d_out;
    float* ws  = (float*)d_ws;

    void* args[] = { &x, &rnd, &Wc, &bcv, &gate, &lsig, &out, &ws };
    hipLaunchCooperativeKernel((void*)sbseg_kernel, dim3(GRID), dim3(TPB),
                               args, 0, stream);
}

// Round 2
// 1714.487 us; speedup vs baseline: 1.0028x; 1.0028x over previous
//
#include <hip/hip_runtime.h>
#include <hip/hip_cooperative_groups.h>

namespace cg = cooperative_groups;

#define BATCHES 32
#define CIN     64
#define COUT    8
#define HWPIX   65536      // 256*256
#define KSTEPS  11
#define NSTEPS  10         // K_STEPS - 1
#define BPB     8          // blocks per batch
#define GRID    (BATCHES*BPB)   // 256 blocks = 1 per CU
#define TPB     1024
#define PIXB    (HWPIX/BPB)     // 8192 pixels per block
#define GROUPS  2               // 2 float4-groups -> 8 px/thread
#define CSTR    12              // candidate stride in floats: [prob, idx, feat0..7, pad, pad]

union F4 { float4 v; float a[4]; };

// waves_per_eu(4,4): pin occupancy target to 4 waves/EU (16 waves/CU -- the max
// with one 1024-thread block per CU anyway) so the allocator gets the full
// 512/4 = 128 VGPR budget. Round-1 build used launch_bounds(1024,4) (a MINIMUM)
// and the backend chased 8 waves/EU -> 64 VGPRs -> spilled the 80-float
// persistent state to scratch -> VALUBusy 3.7%, 1719 us.
__global__ void
__attribute__((amdgpu_flat_work_group_size(1024, 1024), amdgpu_waves_per_eu(4, 4)))
sbseg_kernel(const float* __restrict__ x, const float* __restrict__ rnd,
             const float* __restrict__ Wc, const float* __restrict__ bcv,
             const float* __restrict__ gatep, const float* __restrict__ lsigp,
             float* __restrict__ out, float* __restrict__ ws)
{
    cg::grid_group grid = cg::this_grid();

    __shared__ float sW[CIN][COUT];   // [c][o] for contiguous per-c reads
    __shared__ float sRed[2 * (TPB/64)];
    __shared__ float sSeed[COUT];
    __shared__ float sBestP;
    __shared__ int   sBestI;
    __shared__ int   sWinB;

    const int tid   = threadIdx.x;
    const int bid   = blockIdx.x;
    const int batch = bid / BPB;
    const int binb  = bid - batch * BPB;
    const int pbase = binb * PIXB;

    // stage conv weights into LDS, transposed to [c][o]
    if (tid < CIN * COUT) {
        int o = tid >> 6, c = tid & 63;      // Wc is [COUT][CIN] row-major
        sW[c][o] = Wc[tid];
    }
    __syncthreads();

    const float gate = gatep[0];
    const float sigma = expf(lsigp[0]);
    const float nrs = -1.0f / sigma;

    // persistent per-thread state: 8 pixels
    float feat[GROUPS][COUT][4];   // 64 VGPRs
    float scope[GROUPS][4];        // 8
    float rv[GROUPS][4];           // 8

#pragma unroll
    for (int g = 0; g < GROUPS; ++g)
#pragma unroll
        for (int o = 0; o < COUT; ++o)
#pragma unroll
            for (int j = 0; j < 4; ++j) feat[g][o][j] = 0.0f;

    // ---- 1x1 conv: feat[o] = sum_c W[o][c] * x[b,c,p] ----
    const float* xb = x + (size_t)batch * CIN * HWPIX + pbase + tid * 4;
#pragma unroll 2
    for (int c = 0; c < CIN; ++c) {
        F4 w0, w1;
        w0.v = *(const float4*)&sW[c][0];
        w1.v = *(const float4*)&sW[c][4];
        const float* xc = xb + (size_t)c * HWPIX;
#pragma unroll
        for (int g = 0; g < GROUPS; ++g) {
            F4 xv; xv.v = *(const float4*)(xc + g * (PIXB / GROUPS));
#pragma unroll
            for (int j = 0; j < 4; ++j) {
                feat[g][0][j] = fmaf(w0.a[0], xv.a[j], feat[g][0][j]);
                feat[g][1][j] = fmaf(w0.a[1], xv.a[j], feat[g][1][j]);
                feat[g][2][j] = fmaf(w0.a[2], xv.a[j], feat[g][2][j]);
                feat[g][3][j] = fmaf(w0.a[3], xv.a[j], feat[g][3][j]);
                feat[g][4][j] = fmaf(w1.a[0], xv.a[j], feat[g][4][j]);
                feat[g][5][j] = fmaf(w1.a[1], xv.a[j], feat[g][5][j]);
                feat[g][6][j] = fmaf(w1.a[2], xv.a[j], feat[g][6][j]);
                feat[g][7][j] = fmaf(w1.a[3], xv.a[j], feat[g][7][j]);
            }
        }
    }

    // ---- feat = gate*(conv + b) + uv ; load rand ; scope = 1 ----
    const float dstep = 2.0f / 255.0f;
    const float* rb = rnd + (size_t)batch * HWPIX + pbase + tid * 4;
#pragma unroll
    for (int g = 0; g < GROUPS; ++g) {
        F4 r4; r4.v = *(const float4*)(rb + g * (PIXB / GROUPS));
#pragma unroll
        for (int j = 0; j < 4; ++j) {
            rv[g][j] = r4.a[j];
            int p = pbase + g * (PIXB / GROUPS) + tid * 4 + j;
            float gx = -1.0f + dstep * (float)(p >> 8);   // row channel (C_OUT-2)
            float gy = -1.0f + dstep * (float)(p & 255);  // col channel (C_OUT-1)
#pragma unroll
            for (int o = 0; o < COUT; ++o) {
                float u = (o == COUT - 2) ? gx : ((o == COUT - 1) ? gy : 0.0f);
                feat[g][o][j] = gate * (feat[g][o][j] + bcv[o]) + u;
            }
            scope[g][j] = 1.0f;
        }
    }

    float* masksOut  = out;
    float* scopesOut = out + (size_t)BATCHES * KSTEPS * HWPIX;

    // scopes[:,0,:,:] = 1
    {
        F4 one; one.a[0] = one.a[1] = one.a[2] = one.a[3] = 1.0f;
#pragma unroll
        for (int g = 0; g < GROUPS; ++g)
            *(float4*)(scopesOut + (size_t)batch * KSTEPS * HWPIX + pbase + tid * 4 + g * (PIXB / GROUPS)) = one.v;
    }

    // ---- stick-breaking loop ----
    for (int k = 0; k < NSTEPS; ++k) {
        // 1) local argmax of prob = rand * scope (tie -> lowest index)
        float bp = -1.0f; int bi = 0x7FFFFFFF;
#pragma unroll
        for (int g = 0; g < GROUPS; ++g)
#pragma unroll
            for (int j = 0; j < 4; ++j) {
                float pr = rv[g][j] * scope[g][j];
                int idx = pbase + g * (PIXB / GROUPS) + tid * 4 + j;
                if (pr > bp) { bp = pr; bi = idx; }   // ascending idx order => strict > keeps first
            }
        // wave reduce (64 lanes)
#pragma unroll
        for (int off = 32; off > 0; off >>= 1) {
            float op = __shfl_down(bp, off);
            int   oi = __shfl_down(bi, off);
            if (op > bp || (op == bp && oi < bi)) { bp = op; bi = oi; }
        }
        int wv = tid >> 6;
        if ((tid & 63) == 0) { sRed[wv * 2] = bp; ((int*)sRed)[wv * 2 + 1] = bi; }
        __syncthreads();
        if (tid == 0) {
            float p = sRed[0]; int i = ((int*)sRed)[1];
            for (int w = 1; w < TPB / 64; ++w) {
                float op = sRed[w * 2]; int oi = ((int*)sRed)[w * 2 + 1];
                if (op > p || (op == p && oi < i)) { p = op; i = oi; }
            }
            sBestP = p; sBestI = i;
        }
        __syncthreads();
        const float bestP = sBestP; const int bestI = sBestI;

        // 2) owner thread writes candidate {prob, idx, feat[8]} (double-buffered by parity)
        float* myCand = ws + ((size_t)((k & 1) * GRID + bid)) * CSTR;
#pragma unroll
        for (int g = 0; g < GROUPS; ++g)
#pragma unroll
            for (int j = 0; j < 4; ++j) {
                int idx = pbase + g * (PIXB / GROUPS) + tid * 4 + j;
                if (idx == bestI) {
                    myCand[0] = bestP;
                    ((int*)myCand)[1] = bestI;
#pragma unroll
                    for (int o = 0; o < COUT; ++o) myCand[2 + o] = feat[g][o][j];
                }
            }
        __threadfence();
        grid.sync();

        // 3) every block reduces its batch's BPB candidates (redundantly; L2 broadcast)
        if (tid < 64) {
            float p = -1.0f; int i = 0x7FFFFFFF; int wb = 0;
            if (tid < BPB) {
                const float* cc = ws + ((size_t)((k & 1) * GRID + batch * BPB + tid)) * CSTR;
                p = cc[0]; i = ((const int*)cc)[1]; wb = tid;
            }
#pragma unroll
            for (int off = 32; off > 0; off >>= 1) {
                float op = __shfl_down(p, off);
                int   oi = __shfl_down(i, off);
                int   ob = __shfl_down(wb, off);
                if (op > p || (op == p && oi < i)) { p = op; i = oi; wb = ob; }
            }
            if (tid == 0) sWinB = wb;
        }
        __syncthreads();
        if (tid < COUT)
            sSeed[tid] = ws[((size_t)((k & 1) * GRID + batch * BPB + sWinB)) * CSTR + 2 + tid];
        __syncthreads();

        float sd[COUT];
#pragma unroll
        for (int o = 0; o < COUT; ++o) sd[o] = sSeed[o];

        // 4) pointwise: alpha = clip(exp(-sqdist/sigma)); mask = scope*a; scope *= 1-a
#pragma unroll
        for (int g = 0; g < GROUPS; ++g) {
            F4 mo, so;
#pragma unroll
            for (int j = 0; j < 4; ++j) {
                float sq = 0.0f;
#pragma unroll
                for (int o = 0; o < COUT; ++o) {
                    float d = feat[g][o][j] - sd[o];
                    sq = fmaf(d, d, sq);
                }
                float alpha = expf(sq * nrs);
                alpha = fminf(fmaxf(alpha, 0.01f), 0.99f);
                mo.a[j] = scope[g][j] * alpha;
                scope[g][j] *= (1.0f - alpha);
                so.a[j] = scope[g][j];
            }
            size_t off = (size_t)pbase + tid * 4 + g * (PIXB / GROUPS);
            *(float4*)(masksOut  + ((size_t)(batch * KSTEPS + k))     * HWPIX + off) = mo.v;
            *(float4*)(scopesOut + ((size_t)(batch * KSTEPS + k + 1)) * HWPIX + off) = so.v;
        }
    }

    // masks[:,K-1] = remaining scope
#pragma unroll
    for (int g = 0; g < GROUPS; ++g) {
        F4 so;
#pragma unroll
        for (int j = 0; j < 4; ++j) so.a[j] = scope[g][j];
        *(float4*)(masksOut + ((size_t)(batch * KSTEPS + NSTEPS)) * HWPIX
                   + pbase + tid * 4 + g * (PIXB / GROUPS)) = so.v;
    }
}

extern "C" void kernel_launch(void* const* d_in, const int* in_sizes, int n_in,
                              void* d_out, int out_size, void* d_ws, size_t ws_size,
                              hipStream_t stream) {
    const float* x    = (const float*)d_in[0];
    const float* rnd  = (const float*)d_in[1];
    const float* Wc   = (const float*)d_in[2];
    const float* bcv  = (const float*)d_in[3];
    const float* gate = (const float*)d_in[4];
    const float* lsig = (const float*)d_in[5];
    float* out = (float*)d_out;
    float* ws  = (float*)d_ws;

    void* args[] = { &x, &rnd, &Wc, &bcv, &gate, &lsig, &out, &ws };
    hipLaunchCooperativeKernel((void*)sbseg_kernel, dim3(GRID), dim3(TPB),
                               args, 0, stream);
}